// Round 1
// baseline (5902.262 us; speedup 1.0000x reference)
//
#include <hip/hip_runtime.h>

#define N_TOK 65536
#define DIM 256
#define KCB 1024
#define NLVL 8
#define TPB 32                       // tokens per block
#define ND_OUT (N_TOK * DIM)         // 16777216
#define IDX_OFF ND_OUT
#define SC_OFF (ND_OUT + N_TOK * NLVL) // 17301504
#define EPSV 1e-6f

__device__ __forceinline__ float wave_red(float v) {
    v += __shfl_xor(v, 32, 64);
    v += __shfl_xor(v, 16, 64);
    v += __shfl_xor(v, 8, 64);
    v += __shfl_xor(v, 4, 64);
    v += __shfl_xor(v, 2, 64);
    v += __shfl_xor(v, 1, 64);
    return v;
}

// order-preserving float->uint map (monotone increasing)
__device__ __forceinline__ unsigned int ordf(float d) {
    unsigned int u = __float_as_uint(d);
    return (u & 0x80000000u) ? ~u : (u ^ 0x80000000u);
}

// ---------------- c_sq precompute + ws zeroing ----------------
__global__ __launch_bounds__(256) void k_csq(const float* __restrict__ cbs,
                                             float* __restrict__ csq,
                                             int* __restrict__ gcounts,
                                             float* __restrict__ gloss) {
    const int tid = threadIdx.x;
    const int wv = tid >> 6, lane = tid & 63;
    const int code = blockIdx.x * 4 + wv; // 0..8191 (lvl*1024 + k)
    const float4 v = *(const float4*)(cbs + (size_t)code * DIM + lane * 4);
    float s = v.x * v.x + v.y * v.y + v.z * v.z + v.w * v.w;
    s = wave_red(s);
    if (lane == 0) csq[code] = s;
    if (blockIdx.x == 0) {
#pragma unroll
        for (int i = 0; i < 4; ++i) gcounts[tid + i * 256] = 0;
        if (tid == 0) *gloss = 0.f;
    }
}

// ---------------- fused RVQ: all 8 levels in one kernel ----------------
__global__ __launch_bounds__(256, 2) void k_main(const float* __restrict__ z,
                                                 const float* __restrict__ cbs,
                                                 const float* __restrict__ csq,
                                                 float* __restrict__ out,
                                                 int* __restrict__ gcounts,
                                                 float* __restrict__ gloss) {
    __shared__ __align__(16) float Rld[TPB * DIM];   // 32 KB residual, row-major
    __shared__ __align__(16) float Cld[32 * 256];    // 32 KB codebook slice, [dim][code] swizzled
    __shared__ int bestI[TPB];
    __shared__ int idxBuf[TPB * NLVL];
    __shared__ int hist[KCB];
    __shared__ float wpart[4];

    const int tid = threadIdx.x;
    const int lane = tid & 63, wv = tid >> 6;
    const int cg = tid & 31, tg = tid >> 5;
    const int t0 = blockIdx.x * TPB;

    // stage z -> Rld (coalesced), zero histogram
#pragma unroll
    for (int i = 0; i < 8; ++i) {
        int fi = tid + i * 256;          // float4 index 0..2047
        int row = fi >> 6, col = fi & 63;
        *(float4*)&Rld[row * DIM + col * 4] =
            *(const float4*)(z + (size_t)(t0 + row) * DIM + col * 4);
    }
#pragma unroll
    for (int i = 0; i < 4; ++i) hist[tid + i * 256] = 0;

    float4 qs[8];
#pragma unroll
    for (int s = 0; s < 8; ++s) qs[s] = make_float4(0.f, 0.f, 0.f, 0.f);
    float loss_acc = 0.f;

    __syncthreads();

    for (int lvl = 0; lvl < NLVL; ++lvl) {
        const float* cb = cbs + (size_t)lvl * KCB * DIM;
        unsigned long long bkey[4] = {~0ull, ~0ull, ~0ull, ~0ull};

        for (int chunk = 0; chunk < 4; ++chunk) {      // 256 codes per chunk
            float accL[4][4] = {};
            float accH[4][4] = {};
            for (int slc = 0; slc < 8; ++slc) {        // 32 dims per slice
                __syncthreads();                       // prior reads of Cld done
                {
                    const int f = tid & 7, crow = tid >> 3;
#pragma unroll
                    for (int pass = 0; pass < 8; ++pass) {
                        int c = crow + pass * 32;      // code within chunk, 0..255
                        const float4 v = *(const float4*)(cb +
                            (size_t)(chunk * 256 + c) * DIM + slc * 32 + f * 4);
                        // transpose into [dim][code] with group-XOR swizzle (dim/4 == f)
                        int col = (((c >> 2) ^ f) << 2) + (c & 3);
                        Cld[(f * 4 + 0) * 256 + col] = v.x;
                        Cld[(f * 4 + 1) * 256 + col] = v.y;
                        Cld[(f * 4 + 2) * 256 + col] = v.z;
                        Cld[(f * 4 + 3) * 256 + col] = v.w;
                    }
                }
                __syncthreads();
                const int sA = slc * 32;
#pragma unroll
                for (int d4 = 0; d4 < 8; ++d4) {
                    float r[4][4];
#pragma unroll
                    for (int i = 0; i < 4; ++i) {
                        float4 rv = *(const float4*)&Rld[(tg * 4 + i) * DIM + sA + d4 * 4];
                        r[i][0] = rv.x; r[i][1] = rv.y; r[i][2] = rv.z; r[i][3] = rv.w;
                    }
                    float cl[4][4], ch[4][4];
                    const int gl = ((cg ^ d4) << 2);
                    const int gh = ((32 + (cg ^ d4)) << 2);
#pragma unroll
                    for (int k = 0; k < 4; ++k) {
                        int dd = d4 * 4 + k;
                        float4 a = *(const float4*)&Cld[dd * 256 + gl];
                        cl[k][0] = a.x; cl[k][1] = a.y; cl[k][2] = a.z; cl[k][3] = a.w;
                        float4 b = *(const float4*)&Cld[dd * 256 + gh];
                        ch[k][0] = b.x; ch[k][1] = b.y; ch[k][2] = b.z; ch[k][3] = b.w;
                    }
#pragma unroll
                    for (int i = 0; i < 4; ++i)
#pragma unroll
                        for (int k = 0; k < 4; ++k)
#pragma unroll
                            for (int j = 0; j < 4; ++j) {
                                accL[i][j] = fmaf(r[i][k], cl[k][j], accL[i][j]);
                                accH[i][j] = fmaf(r[i][k], ch[k][j], accH[i][j]);
                            }
                }
            }
            // distances + running argmin (tie -> smaller index, like np.argmin)
            const float4 ql = *(const float4*)(csq + lvl * KCB + chunk * 256 + cg * 4);
            const float4 qh = *(const float4*)(csq + lvl * KCB + chunk * 256 + 128 + cg * 4);
            const float qla[4] = {ql.x, ql.y, ql.z, ql.w};
            const float qha[4] = {qh.x, qh.y, qh.z, qh.w};
            const int cbase = chunk * 256 + cg * 4;
#pragma unroll
            for (int i = 0; i < 4; ++i)
#pragma unroll
                for (int j = 0; j < 4; ++j) {
                    float dL = qla[j] - 2.f * accL[i][j];
                    unsigned long long kL =
                        ((unsigned long long)ordf(dL) << 10) | (unsigned)(cbase + j);
                    if (kL < bkey[i]) bkey[i] = kL;
                    float dH = qha[j] - 2.f * accH[i][j];
                    unsigned long long kH =
                        ((unsigned long long)ordf(dH) << 10) | (unsigned)(cbase + 128 + j);
                    if (kH < bkey[i]) bkey[i] = kH;
                }
        }
        // reduce across the 32 lanes sharing tg (half-wave, masks <= 16)
#pragma unroll
        for (int m = 16; m >= 1; m >>= 1)
#pragma unroll
            for (int i = 0; i < 4; ++i) {
                unsigned long long o = __shfl_xor(bkey[i], m, 64);
                if (o < bkey[i]) bkey[i] = o;
            }
        if (cg == 0)
#pragma unroll
            for (int i = 0; i < 4; ++i) bestI[tg * 4 + i] = (int)(bkey[i] & 1023ull);
        __syncthreads();

        // epilogue: wave wv owns tokens wv*8 .. wv*8+7; lane owns dims lane*4..+3
        for (int s = 0; s < 8; ++s) {
            const int tl = wv * 8 + s;
            const int idx = bestI[tl];
            float4 r4 = *(const float4*)&Rld[tl * DIM + lane * 4];
            float4 c4 = *(const float4*)(cb + (size_t)idx * DIM + lane * 4);
            float rr = r4.x * r4.x + r4.y * r4.y + r4.z * r4.z + r4.w * r4.w;
            float cc = c4.x * c4.x + c4.y * c4.y + c4.z * c4.z + c4.w * c4.w;
            float e0 = (c4.x - r4.x) * (c4.x - r4.x) + (c4.y - r4.y) * (c4.y - r4.y) +
                       (c4.z - r4.z) * (c4.z - r4.z) + (c4.w - r4.w) * (c4.w - r4.w);
            rr = wave_red(rr);
            cc = wave_red(cc);
            e0 = wave_red(e0);
            const float dx = fmaxf(sqrtf(rr), EPSV);
            const float dc = fmaxf(sqrtf(cc), EPSV);
            float4 u4 = make_float4(r4.x / dx, r4.y / dx, r4.z / dx, r4.w / dx);
            float4 q4 = make_float4(c4.x / dc, c4.y / dc, c4.z / dc, c4.w / dc);
            float4 w4 = make_float4(u4.x + q4.x, u4.y + q4.y, u4.z + q4.z, u4.w + q4.w);
            float ww = w4.x * w4.x + w4.y * w4.y + w4.z * w4.z + w4.w * w4.w;
            float xw = r4.x * w4.x + r4.y * w4.y + r4.z * w4.z + r4.w * w4.w;
            float xu = r4.x * u4.x + r4.y * u4.y + r4.z * u4.z + r4.w * u4.w;
            ww = wave_red(ww);
            xw = wave_red(xw);
            xu = wave_red(xu);
            const float dw = fmaxf(sqrtf(ww), EPSV);
            const float xwn = xw / dw;
            float4 wn = make_float4(w4.x / dw, w4.y / dw, w4.z / dw, w4.w / dw);
            float4 zst = make_float4(r4.x - 2.f * xwn * wn.x + 2.f * xu * q4.x,
                                     r4.y - 2.f * xwn * wn.y + 2.f * xu * q4.y,
                                     r4.z - 2.f * xwn * wn.z + 2.f * xu * q4.z,
                                     r4.w - 2.f * xwn * wn.w + 2.f * xu * q4.w);
            float4 rn = make_float4(r4.x - zst.x, r4.y - zst.y, r4.z - zst.z, r4.w - zst.w);
            *(float4*)&Rld[tl * DIM + lane * 4] = rn;
            qs[s].x += c4.x; qs[s].y += c4.y; qs[s].z += c4.z; qs[s].w += c4.w;
            loss_acc += e0;
            if (lane == 0) {
                idxBuf[tl * NLVL + lvl] = idx;
                atomicAdd(&hist[idx], 1);
            }
        }
        __syncthreads();
    }

    // z_q = z + (quantized_sum - z)
    for (int s = 0; s < 8; ++s) {
        const int trow = t0 + wv * 8 + s;
        float4 z4 = *(const float4*)(z + (size_t)trow * DIM + lane * 4);
        float4 q = qs[s];
        float4 o = make_float4(z4.x + (q.x - z4.x), z4.y + (q.y - z4.y),
                               z4.z + (q.z - z4.z), z4.w + (q.w - z4.w));
        *(float4*)(out + (size_t)trow * DIM + lane * 4) = o;
    }
    // indices (as float), [N, 8] row-major
    {
        const int tl = tid >> 3, lv = tid & 7;
        out[IDX_OFF + (size_t)(t0 + tl) * NLVL + lv] = (float)idxBuf[tl * NLVL + lv];
    }
    // histogram flush
#pragma unroll
    for (int i = 0; i < 4; ++i) {
        int b = tid + i * 256;
        int h = hist[b];
        if (h) atomicAdd(&gcounts[b], h);
    }
    // loss partial (uniform across wave after wave_red)
    if (lane == 0) wpart[wv] = loss_acc;
    __syncthreads();
    if (tid == 0) atomicAdd(gloss, wpart[0] + wpart[1] + wpart[2] + wpart[3]);
}

// ---------------- scalars: losses + perplexity ----------------
__global__ __launch_bounds__(256) void k_fin(const int* __restrict__ gcounts,
                                             const float* __restrict__ gloss,
                                             float* __restrict__ out) {
    __shared__ float part[4];
    const int tid = threadIdx.x, lane = tid & 63, wv = tid >> 6;
    float e = 0.f;
#pragma unroll
    for (int i = 0; i < 4; ++i) {
        float c = (float)gcounts[tid * 4 + i];
        float p = c * (1.f / 524288.f);
        if (p > 0.f) e += p * logf(p);
    }
    e = wave_red(e);
    if (lane == 0) part[wv] = e;
    __syncthreads();
    if (tid == 0) {
        float ent = -(part[0] + part[1] + part[2] + part[3]);
        float cbl = *gloss * (1.f / 16777216.f); // sum over levels of per-level means
        out[SC_OFF + 0] = cbl + 0.25f * cbl;     // loss = cb + BETA * commit (commit == cb)
        out[SC_OFF + 1] = cbl;                   // total_codebook_loss
        out[SC_OFF + 2] = cbl;                   // total_commitment_loss
        out[SC_OFF + 3] = expf(ent);             // perplexity
    }
}

extern "C" void kernel_launch(void* const* d_in, const int* in_sizes, int n_in,
                              void* d_out, int out_size, void* d_ws, size_t ws_size,
                              hipStream_t stream) {
    (void)in_sizes; (void)n_in; (void)out_size; (void)ws_size;
    const float* z = (const float*)d_in[0];
    const float* cbs = (const float*)d_in[1];
    float* out = (float*)d_out;
    float* csq = (float*)d_ws;                                   // 8192 floats
    int* gcounts = (int*)((char*)d_ws + 8192 * 4);               // 1024 ints
    float* gloss = (float*)((char*)d_ws + 8192 * 4 + 1024 * 4);  // 1 float

    hipLaunchKernelGGL(k_csq, dim3(2048), dim3(256), 0, stream, cbs, csq, gcounts, gloss);
    hipLaunchKernelGGL(k_main, dim3(2048), dim3(256), 0, stream, z, cbs, csq, out, gcounts, gloss);
    hipLaunchKernelGGL(k_fin, dim3(1), dim3(256), 0, stream, gcounts, gloss, out);
}

// Round 2
// 1710.515 us; speedup vs baseline: 3.4506x; 3.4506x over previous
//
#include <hip/hip_runtime.h>

#define N_TOK 65536
#define DIM 256
#define KCB 1024
#define NLVL 8
#define TPB 64                        // tokens per block (k_main)
#define ND_OUT (N_TOK * DIM)          // 16777216
#define IDX_OFF ND_OUT
#define SC_OFF (ND_OUT + N_TOK * NLVL) // 17301504
#define EPSV 1e-6f

typedef _Float16 half8 __attribute__((ext_vector_type(8)));
typedef float f32x4 __attribute__((ext_vector_type(4)));

__device__ __forceinline__ float wave_red(float v) {
    v += __shfl_xor(v, 32, 64);
    v += __shfl_xor(v, 16, 64);
    v += __shfl_xor(v, 8, 64);
    v += __shfl_xor(v, 4, 64);
    v += __shfl_xor(v, 2, 64);
    v += __shfl_xor(v, 1, 64);
    return v;
}

// order-preserving float->uint map (monotone increasing)
__device__ __forceinline__ unsigned int ordf(float d) {
    unsigned int u = __float_as_uint(d);
    return (u & 0x80000000u) ? ~u : (u ^ 0x80000000u);
}

// ---------------- B-fragment precompute (fp16 hi/lo split, scaled) ----------------
// layout: for frag F = (lvl*64 + nt)*8 + s : [hi: 64 lanes x half8][lo: 64 lanes x half8]
// lane l holds C[code = nt*16 + (l&15)][dim = s*32 + (l>>4)*8 + j] * 2^(lvl+5)
__global__ __launch_bounds__(256) void k_prep(const float* __restrict__ cbs,
                                              half8* __restrict__ ws_b) {
    const int lvl = blockIdx.x >> 6, nt = blockIdx.x & 63;
    const int lane = threadIdx.x & 63, sg = threadIdx.x >> 6;
    const float sc = (float)(1 << (lvl + 5));
#pragma unroll
    for (int ss = 0; ss < 2; ++ss) {
        const int s = sg + ss * 4;
        const int code = nt * 16 + (lane & 15);
        const int d0 = s * 32 + (lane >> 4) * 8;
        const float* p = cbs + ((size_t)(lvl * KCB + code)) * DIM + d0;
        const float4 va = *(const float4*)p;
        const float4 vb = *(const float4*)(p + 4);
        float f[8] = {va.x, va.y, va.z, va.w, vb.x, vb.y, vb.z, vb.w};
        half8 h, l;
#pragma unroll
        for (int j = 0; j < 8; ++j) {
            float fs = f[j] * sc;
            _Float16 hh = (_Float16)fs;
            h[j] = hh;
            l[j] = (_Float16)(fs - (float)hh);
        }
        const size_t base = ((size_t)((lvl * 64 + nt) * 8 + s)) * 128;
        ws_b[base + lane] = h;
        ws_b[base + 64 + lane] = l;
    }
}

// ---------------- scaled c_sq + ws zeroing ----------------
__global__ __launch_bounds__(256) void k_csq(const float* __restrict__ cbs,
                                             float* __restrict__ csq_s,
                                             int* __restrict__ gcounts,
                                             float* __restrict__ gloss) {
    const int tid = threadIdx.x;
    const int wv = tid >> 6, lane = tid & 63;
    const int code = blockIdx.x * 4 + wv; // 0..8191 (lvl*1024 + k)
    const float4 v = *(const float4*)(cbs + (size_t)code * DIM + lane * 4);
    float s = v.x * v.x + v.y * v.y + v.z * v.z + v.w * v.w;
    s = wave_red(s);
    const int lvl = code >> 10;
    if (lane == 0) csq_s[code] = s * (float)(1 << (10 + lvl));
    if (blockIdx.x == 0) {
#pragma unroll
        for (int i = 0; i < 4; ++i) gcounts[tid + i * 256] = 0;
        if (tid == 0) *gloss = 0.f;
    }
}

// ---------------- fused RVQ main: fp16x4 MFMA distance GEMM ----------------
__global__ __launch_bounds__(512, 2) void k_main(const float* __restrict__ z,
                                                 const float* __restrict__ cbs,
                                                 const half8* __restrict__ ws_b,
                                                 const float* __restrict__ csq_s,
                                                 float* __restrict__ out,
                                                 int* __restrict__ gcounts,
                                                 float* __restrict__ gloss) {
    __shared__ __align__(16) float Rld[TPB * DIM];            // 64 KB, XOR-swizzled fp32 residual
    __shared__ unsigned long long keyBuf[2][4][32];           // 2 KB
    __shared__ int bestI_sh[TPB];
    __shared__ int idxBuf[TPB * NLVL];
    __shared__ int hist[KCB];
    __shared__ float wpart[8];

    const int tid = threadIdx.x;
    const int lane = tid & 63, w = tid >> 6;
    const int g = w >> 2, q = w & 3;   // token-group, code-quarter
    const int t0 = blockIdx.x * TPB;

    // stage z -> Rld (swizzled: dims [4*k4..] stored at col4 = k4 ^ (2*(t&15)))
#pragma unroll
    for (int i = 0; i < 8; ++i) {
        int fi = tid + i * 512;           // float4 index 0..4095
        int t = fi >> 6, k4 = fi & 63;
        *(float4*)&Rld[t * DIM + ((k4 ^ (2 * (t & 15))) << 2)] =
            *(const float4*)(z + (size_t)(t0 + t) * DIM + k4 * 4);
    }
#pragma unroll
    for (int i = 0; i < 2; ++i) hist[tid + i * 512] = 0;
    float loss_acc = 0.f;
    __syncthreads();

    for (int lvl = 0; lvl < NLVL; ++lvl) {
        // ---- A fragments: load residual (fp32), scale x32, split fp16 hi/lo ----
        half8 Ah[2][8], Al[2][8];
#pragma unroll
        for (int m = 0; m < 2; ++m) {
            const int tl = g * 32 + m * 16 + (lane & 15);
            const int e = 2 * (lane & 15);
#pragma unroll
            for (int s = 0; s < 8; ++s) {
                const int k4 = 8 * s + 2 * (lane >> 4);
                float4 va = *(const float4*)&Rld[tl * DIM + ((k4 ^ e) << 2)];
                float4 vb = *(const float4*)&Rld[tl * DIM + (((k4 + 1) ^ e) << 2)];
                float f[8] = {va.x, va.y, va.z, va.w, vb.x, vb.y, vb.z, vb.w};
                half8 h, l;
#pragma unroll
                for (int j = 0; j < 8; ++j) {
                    float fs = f[j] * 32.f;
                    _Float16 hh = (_Float16)fs;
                    h[j] = hh;
                    l[j] = (_Float16)(fs - (float)hh);
                }
                Ah[m][s] = h;
                Al[m][s] = l;
            }
        }
        // ---- scaled c_sq preload for this wave's 16 code-tiles ----
        float csqr[16];
        {
            const float* bc = csq_s + lvl * KCB + q * 256 + (lane & 15);
#pragma unroll
            for (int nt = 0; nt < 16; ++nt) csqr[nt] = bc[nt * 16];
        }
        float bd[8];
        int bi[8];
#pragma unroll
        for (int i = 0; i < 8; ++i) { bd[i] = 3.402823466e38f; bi[i] = 0; }

        // ---- distance GEMM: 16 code-tiles, K=256, software-pipelined B from L2 ----
        const half8* pb = ws_b + ((size_t)(lvl * 64 + q * 16) * 8) * 128 + lane;
        half8 bh = pb[0], bl = pb[64];
        for (int nt = 0; nt < 16; ++nt) {
            f32x4 acc0a = {0.f, 0.f, 0.f, 0.f}, acc0b = acc0a;
            f32x4 acc1a = acc0a, acc1b = acc0a;
#pragma unroll
            for (int s = 0; s < 8; ++s) {
                int fn = nt * 8 + s + 1;
                if (fn > 127) fn = 127;
                half8 nbh = pb[(size_t)fn * 128];
                half8 nbl = pb[(size_t)fn * 128 + 64];
                acc0a = __builtin_amdgcn_mfma_f32_16x16x32_f16(Ah[0][s], bh, acc0a, 0, 0, 0);
                acc1a = __builtin_amdgcn_mfma_f32_16x16x32_f16(Ah[1][s], bh, acc1a, 0, 0, 0);
                acc0b = __builtin_amdgcn_mfma_f32_16x16x32_f16(Al[0][s], bh, acc0b, 0, 0, 0);
                acc1b = __builtin_amdgcn_mfma_f32_16x16x32_f16(Al[1][s], bh, acc1b, 0, 0, 0);
                acc0a = __builtin_amdgcn_mfma_f32_16x16x32_f16(Ah[0][s], bl, acc0a, 0, 0, 0);
                acc1a = __builtin_amdgcn_mfma_f32_16x16x32_f16(Ah[1][s], bl, acc1a, 0, 0, 0);
                acc0b = __builtin_amdgcn_mfma_f32_16x16x32_f16(Al[0][s], bl, acc0b, 0, 0, 0);
                acc1b = __builtin_amdgcn_mfma_f32_16x16x32_f16(Al[1][s], bl, acc1b, 0, 0, 0);
                bh = nbh;
                bl = nbl;
            }
            const f32x4 a0 = acc0a + acc0b;
            const f32x4 a1 = acc1a + acc1b;
            const int code = q * 256 + nt * 16 + (lane & 15);
            const float cs = csqr[nt];
#pragma unroll
            for (int i = 0; i < 4; ++i) {
                float d0 = fmaf(-2.f, a0[i], cs);
                if (d0 < bd[i]) { bd[i] = d0; bi[i] = code; }
                float d1 = fmaf(-2.f, a1[i], cs);
                if (d1 < bd[4 + i]) { bd[4 + i] = d1; bi[4 + i] = code; }
            }
        }
        // ---- argmin cross-lane reduce (packed key: ordered-dist | code) ----
        unsigned long long key[8];
#pragma unroll
        for (int i = 0; i < 8; ++i)
            key[i] = (((unsigned long long)ordf(bd[i])) << 10) | (unsigned long long)bi[i];
#pragma unroll
        for (int m = 1; m <= 8; m <<= 1)
#pragma unroll
            for (int i = 0; i < 8; ++i) {
                unsigned long long o = __shfl_xor(key[i], m, 64);
                if (o < key[i]) key[i] = o;
            }
        if ((lane & 15) == 0) {
            const int qq = lane >> 4;
#pragma unroll
            for (int m = 0; m < 2; ++m)
#pragma unroll
                for (int i = 0; i < 4; ++i)
                    keyBuf[g][q][m * 16 + qq * 4 + i] = key[m * 4 + i];
        }
        __syncthreads();
        if (tid < 64) {
            const int tg = tid >> 5, r = tid & 31;
            unsigned long long k = keyBuf[tg][0][r];
            if (keyBuf[tg][1][r] < k) k = keyBuf[tg][1][r];
            if (keyBuf[tg][2][r] < k) k = keyBuf[tg][2][r];
            if (keyBuf[tg][3][r] < k) k = keyBuf[tg][3][r];
            const int idx = (int)(k & 1023ull);
            bestI_sh[tg * 32 + r] = idx;
            idxBuf[(tg * 32 + r) * NLVL + lvl] = idx;
            atomicAdd(&hist[idx], 1);
        }
        __syncthreads();

        // ---- epilogue: rotation trick + residual update (exact round-1 math) ----
        const float* cb = cbs + (size_t)lvl * KCB * DIM;
        for (int s2 = 0; s2 < 8; ++s2) {
            const int tl = w * 8 + s2;
            const int idx = bestI_sh[tl];
            const int e = 2 * (tl & 15);
            float4 r4 = *(const float4*)&Rld[tl * DIM + ((lane ^ e) << 2)];
            float4 c4 = *(const float4*)(cb + (size_t)idx * DIM + lane * 4);
            float rr = r4.x * r4.x + r4.y * r4.y + r4.z * r4.z + r4.w * r4.w;
            float cc = c4.x * c4.x + c4.y * c4.y + c4.z * c4.z + c4.w * c4.w;
            float e0 = (c4.x - r4.x) * (c4.x - r4.x) + (c4.y - r4.y) * (c4.y - r4.y) +
                       (c4.z - r4.z) * (c4.z - r4.z) + (c4.w - r4.w) * (c4.w - r4.w);
            rr = wave_red(rr);
            cc = wave_red(cc);
            e0 = wave_red(e0);
            const float dx = fmaxf(sqrtf(rr), EPSV);
            const float dc = fmaxf(sqrtf(cc), EPSV);
            float4 u4 = make_float4(r4.x / dx, r4.y / dx, r4.z / dx, r4.w / dx);
            float4 q4 = make_float4(c4.x / dc, c4.y / dc, c4.z / dc, c4.w / dc);
            float4 w4 = make_float4(u4.x + q4.x, u4.y + q4.y, u4.z + q4.z, u4.w + q4.w);
            float ww = w4.x * w4.x + w4.y * w4.y + w4.z * w4.z + w4.w * w4.w;
            float xw = r4.x * w4.x + r4.y * w4.y + r4.z * w4.z + r4.w * w4.w;
            float xu = r4.x * u4.x + r4.y * u4.y + r4.z * u4.z + r4.w * u4.w;
            ww = wave_red(ww);
            xw = wave_red(xw);
            xu = wave_red(xu);
            const float dw = fmaxf(sqrtf(ww), EPSV);
            const float xwn = xw / dw;
            float4 wn = make_float4(w4.x / dw, w4.y / dw, w4.z / dw, w4.w / dw);
            float4 zst = make_float4(r4.x - 2.f * xwn * wn.x + 2.f * xu * q4.x,
                                     r4.y - 2.f * xwn * wn.y + 2.f * xu * q4.y,
                                     r4.z - 2.f * xwn * wn.z + 2.f * xu * q4.z,
                                     r4.w - 2.f * xwn * wn.w + 2.f * xu * q4.w);
            float4 rn = make_float4(r4.x - zst.x, r4.y - zst.y, r4.z - zst.z, r4.w - zst.w);
            *(float4*)&Rld[tl * DIM + ((lane ^ e) << 2)] = rn;
            loss_acc += e0;
        }
        __syncthreads();
    }

    // ---- outputs: z_q = z + (sum_l c[idx_l] - z) ----
    for (int s2 = 0; s2 < 8; ++s2) {
        const int tl = w * 8 + s2;
        const size_t trow = t0 + tl;
        float4 z4 = *(const float4*)(z + trow * DIM + lane * 4);
        float4 qs = make_float4(0.f, 0.f, 0.f, 0.f);
#pragma unroll
        for (int lvl = 0; lvl < NLVL; ++lvl) {
            const int idx = idxBuf[tl * NLVL + lvl];
            float4 c4 = *(const float4*)(cbs + ((size_t)(lvl * KCB + idx)) * DIM + lane * 4);
            qs.x += c4.x; qs.y += c4.y; qs.z += c4.z; qs.w += c4.w;
        }
        float4 o = make_float4(z4.x + (qs.x - z4.x), z4.y + (qs.y - z4.y),
                               z4.z + (qs.z - z4.z), z4.w + (qs.w - z4.w));
        *(float4*)(out + trow * DIM + lane * 4) = o;
    }
    // indices as float, [N, 8]
    out[IDX_OFF + (size_t)(t0 + (tid >> 3)) * NLVL + (tid & 7)] = (float)idxBuf[tid];
    // histogram flush
#pragma unroll
    for (int i = 0; i < 2; ++i) {
        int b = tid + i * 512;
        int h = hist[b];
        if (h) atomicAdd(&gcounts[b], h);
    }
    // loss partial
    if (lane == 0) wpart[w] = loss_acc;
    __syncthreads();
    if (tid == 0) {
        float sum = 0.f;
#pragma unroll
        for (int i = 0; i < 8; ++i) sum += wpart[i];
        atomicAdd(gloss, sum);
    }
}

// ---------------- scalars: losses + perplexity ----------------
__global__ __launch_bounds__(256) void k_fin(const int* __restrict__ gcounts,
                                             const float* __restrict__ gloss,
                                             float* __restrict__ out) {
    __shared__ float part[4];
    const int tid = threadIdx.x, lane = tid & 63, wv = tid >> 6;
    float e = 0.f;
#pragma unroll
    for (int i = 0; i < 4; ++i) {
        float c = (float)gcounts[tid * 4 + i];
        float p = c * (1.f / 524288.f);
        if (p > 0.f) e += p * logf(p);
    }
    e = wave_red(e);
    if (lane == 0) part[wv] = e;
    __syncthreads();
    if (tid == 0) {
        float ent = -(part[0] + part[1] + part[2] + part[3]);
        float cbl = *gloss * (1.f / 16777216.f);
        out[SC_OFF + 0] = cbl + 0.25f * cbl;
        out[SC_OFF + 1] = cbl;
        out[SC_OFF + 2] = cbl;
        out[SC_OFF + 3] = expf(ent);
    }
}

extern "C" void kernel_launch(void* const* d_in, const int* in_sizes, int n_in,
                              void* d_out, int out_size, void* d_ws, size_t ws_size,
                              hipStream_t stream) {
    (void)in_sizes; (void)n_in; (void)out_size; (void)ws_size;
    const float* z = (const float*)d_in[0];
    const float* cbs = (const float*)d_in[1];
    float* out = (float*)d_out;
    half8* ws_b = (half8*)d_ws;                                    // 8 MB fragments
    float* csq = (float*)((char*)d_ws + (8u << 20));               // 32 KB
    int* gcounts = (int*)((char*)d_ws + (8u << 20) + 32768);       // 4 KB
    float* gloss = (float*)((char*)d_ws + (8u << 20) + 32768 + 4096);

    hipLaunchKernelGGL(k_prep, dim3(512), dim3(256), 0, stream, cbs, ws_b);
    hipLaunchKernelGGL(k_csq, dim3(2048), dim3(256), 0, stream, cbs, csq, gcounts, gloss);
    hipLaunchKernelGGL(k_main, dim3(1024), dim3(512), 0, stream, z, cbs, ws_b, csq, out,
                       gcounts, gloss);
    hipLaunchKernelGGL(k_fin, dim3(1), dim3(256), 0, stream, gcounts, gloss, out);
}

// Round 3
// 1459.074 us; speedup vs baseline: 4.0452x; 1.1723x over previous
//
#include <hip/hip_runtime.h>

#define N_TOK 65536
#define DIM 256
#define KCB 1024
#define NLVL 8
#define TPB 32                        // tokens per block (k_main)
#define ND_OUT (N_TOK * DIM)          // 16777216
#define IDX_OFF ND_OUT
#define SC_OFF (ND_OUT + N_TOK * NLVL) // 17301504
#define EPSV 1e-6f

typedef _Float16 half8 __attribute__((ext_vector_type(8)));
typedef float f32x4 __attribute__((ext_vector_type(4)));

__device__ __forceinline__ float wave_red(float v) {
    v += __shfl_xor(v, 32, 64);
    v += __shfl_xor(v, 16, 64);
    v += __shfl_xor(v, 8, 64);
    v += __shfl_xor(v, 4, 64);
    v += __shfl_xor(v, 2, 64);
    v += __shfl_xor(v, 1, 64);
    return v;
}

// order-preserving float->uint map (monotone increasing)
__device__ __forceinline__ unsigned int ordf(float d) {
    unsigned int u = __float_as_uint(d);
    return (u & 0x80000000u) ? ~u : (u ^ 0x80000000u);
}

// ---------------- B-fragment precompute (fp16 hi/lo RNE split, scaled) ----------------
// layout: frag F = (lvl*8 + s)*64 + nt_g ; at F*128: [hi: 64 x half8][lo: 64 x half8]
// lane l holds C[code = nt_g*16 + (l&15)][dim = s*32 + (l>>4)*8 + j] * 2^(lvl+5)
__global__ __launch_bounds__(256) void k_prep(const float* __restrict__ cbs,
                                              half8* __restrict__ ws_b) {
    const int lvl = blockIdx.x >> 6, ntg = blockIdx.x & 63;
    const int lane = threadIdx.x & 63, sg = threadIdx.x >> 6;
    const float sc = (float)(1 << (lvl + 5));
#pragma unroll
    for (int ss = 0; ss < 2; ++ss) {
        const int s = sg + ss * 4;
        const int code = ntg * 16 + (lane & 15);
        const int d0 = s * 32 + (lane >> 4) * 8;
        const float* p = cbs + ((size_t)(lvl * KCB + code)) * DIM + d0;
        const float4 va = *(const float4*)p;
        const float4 vb = *(const float4*)(p + 4);
        float f[8] = {va.x, va.y, va.z, va.w, vb.x, vb.y, vb.z, vb.w};
        half8 h, l;
#pragma unroll
        for (int j = 0; j < 8; ++j) {
            float fs = f[j] * sc;
            _Float16 hh = (_Float16)fs;          // RNE
            h[j] = hh;
            l[j] = (_Float16)(fs - (float)hh);   // RNE
        }
        const size_t base = ((size_t)((lvl * 8 + s) * 64 + ntg)) * 128;
        ws_b[base + lane] = h;
        ws_b[base + 64 + lane] = l;
    }
}

// ---------------- scaled c_sq + ws zeroing ----------------
__global__ __launch_bounds__(256) void k_csq(const float* __restrict__ cbs,
                                             float* __restrict__ csq_s,
                                             int* __restrict__ gcounts,
                                             float* __restrict__ gloss) {
    const int tid = threadIdx.x;
    const int wv = tid >> 6, lane = tid & 63;
    const int code = blockIdx.x * 4 + wv; // 0..8191 (lvl*1024 + k)
    const float4 v = *(const float4*)(cbs + (size_t)code * DIM + lane * 4);
    float s = v.x * v.x + v.y * v.y + v.z * v.z + v.w * v.w;
    s = wave_red(s);
    const int lvl = code >> 10;
    if (lane == 0) csq_s[code] = s * (float)(1 << (10 + lvl));
    if (blockIdx.x == 0) {
#pragma unroll
        for (int i = 0; i < 4; ++i) gcounts[tid + i * 256] = 0;
        if (tid == 0) *gloss = 0.f;
    }
}

// ---------------- fused RVQ main ----------------
// 256 threads = 4 waves; all waves share the block's 32 tokens (M=32);
// wave q covers codes [q*256, q*256+256) in two halves of 8 code-tiles.
__global__ __launch_bounds__(256, 4) void k_main(const float* __restrict__ z,
                                                 const float* __restrict__ cbs,
                                                 const half8* __restrict__ ws_b,
                                                 const float* __restrict__ csq_s,
                                                 float* __restrict__ out,
                                                 int* __restrict__ gcounts,
                                                 float* __restrict__ gloss) {
    __shared__ __align__(16) float Rld[TPB * DIM];     // 32 KB, x32-scaled, col4 = k4 ^ (t&15)
    __shared__ unsigned long long keyBuf[4][TPB];      // 1 KB
    __shared__ int bestI_sh[TPB];
    __shared__ int idxBuf[TPB * NLVL];
    __shared__ int hist[KCB];
    __shared__ float wpart[4];

    const int tid = threadIdx.x;
    const int lane = tid & 63, q = tid >> 6;
    const int l15 = lane & 15, qd = lane >> 4;
    const int t0 = blockIdx.x * TPB;

    // stage z -> Rld, pre-scaled by 32 (exact pow2), swizzled
#pragma unroll
    for (int i = 0; i < 8; ++i) {
        int fi = tid + i * 256;          // float4 index 0..2047
        int t = fi >> 6, k4 = fi & 63;
        float4 v = *(const float4*)(z + (size_t)(t0 + t) * DIM + k4 * 4);
        v.x *= 32.f; v.y *= 32.f; v.z *= 32.f; v.w *= 32.f;
        *(float4*)&Rld[t * DIM + ((k4 ^ (t & 15)) << 2)] = v;
    }
#pragma unroll
    for (int i = 0; i < 4; ++i) hist[tid + i * 256] = 0;
    float loss_acc = 0.f;
    __syncthreads();

    for (int lvl = 0; lvl < NLVL; ++lvl) {
        float bd[8];
        int bi[8];
#pragma unroll
        for (int i = 0; i < 8; ++i) { bd[i] = 3.402823466e38f; bi[i] = 0; }

        for (int hf = 0; hf < 2; ++hf) {
            f32x4 acc[8][2];
#pragma unroll
            for (int nt = 0; nt < 8; ++nt)
#pragma unroll
                for (int m = 0; m < 2; ++m) acc[nt][m] = (f32x4){0.f, 0.f, 0.f, 0.f};

#pragma unroll 1
            for (int s = 0; s < 8; ++s) {
                // ---- A fragments for this s: read swizzled Rld, RNE hi/lo split ----
                half8 Ah[2], Al[2];
#pragma unroll
                for (int m = 0; m < 2; ++m) {
                    const int row = (m * 16 + l15) * DIM;
                    const int k4 = 8 * s + 2 * qd;
                    float4 va = *(const float4*)&Rld[row + ((k4 ^ l15) << 2)];
                    float4 vb = *(const float4*)&Rld[row + (((k4 + 1) ^ l15) << 2)];
                    float f[8] = {va.x, va.y, va.z, va.w, vb.x, vb.y, vb.z, vb.w};
                    half8 h, l;
#pragma unroll
                    for (int j = 0; j < 8; ++j) {
                        _Float16 hh = (_Float16)f[j];
                        h[j] = hh;
                        l[j] = (_Float16)(f[j] - (float)hh);
                    }
                    Ah[m] = h;
                    Al[m] = l;
                }
                // ---- B stream (L2), software-pipelined ----
                const half8* pb = ws_b +
                    (((size_t)(lvl * 8 + s)) * 64 + q * 16 + hf * 8) * 128 + lane;
                half8 bh = pb[0], bl = pb[64];
#pragma unroll
                for (int nt = 0; nt < 8; ++nt) {
                    const int off = (nt < 7) ? (nt + 1) * 128 : (s < 7 ? 64 * 128 : 0);
                    half8 nbh = pb[off];
                    half8 nbl = pb[off + 64];
                    acc[nt][0] = __builtin_amdgcn_mfma_f32_16x16x32_f16(Ah[0], bh, acc[nt][0], 0, 0, 0);
                    acc[nt][1] = __builtin_amdgcn_mfma_f32_16x16x32_f16(Ah[1], bh, acc[nt][1], 0, 0, 0);
                    acc[nt][0] = __builtin_amdgcn_mfma_f32_16x16x32_f16(Al[0], bh, acc[nt][0], 0, 0, 0);
                    acc[nt][1] = __builtin_amdgcn_mfma_f32_16x16x32_f16(Al[1], bh, acc[nt][1], 0, 0, 0);
                    acc[nt][0] = __builtin_amdgcn_mfma_f32_16x16x32_f16(Ah[0], bl, acc[nt][0], 0, 0, 0);
                    acc[nt][1] = __builtin_amdgcn_mfma_f32_16x16x32_f16(Ah[1], bl, acc[nt][1], 0, 0, 0);
                    acc[nt][0] = __builtin_amdgcn_mfma_f32_16x16x32_f16(Al[0], bl, acc[nt][0], 0, 0, 0);
                    acc[nt][1] = __builtin_amdgcn_mfma_f32_16x16x32_f16(Al[1], bl, acc[nt][1], 0, 0, 0);
                    bh = nbh;
                    bl = nbl;
                }
            }
            // ---- distances + running argmin for this half ----
            const float* csqp = csq_s + lvl * KCB + q * 256 + hf * 128 + l15;
#pragma unroll
            for (int nt = 0; nt < 8; ++nt) {
                const float cs = csqp[nt * 16];
                const int code = q * 256 + hf * 128 + nt * 16 + l15;
#pragma unroll
                for (int i = 0; i < 4; ++i) {
                    float d0 = fmaf(-2.f, acc[nt][0][i], cs);
                    if (d0 < bd[i]) { bd[i] = d0; bi[i] = code; }
                    float d1 = fmaf(-2.f, acc[nt][1][i], cs);
                    if (d1 < bd[4 + i]) { bd[4 + i] = d1; bi[4 + i] = code; }
                }
            }
        }
        // ---- argmin cross-lane reduce over the 16 code-lanes ----
        unsigned long long key[8];
#pragma unroll
        for (int i = 0; i < 8; ++i)
            key[i] = (((unsigned long long)ordf(bd[i])) << 10) | (unsigned long long)bi[i];
#pragma unroll
        for (int m = 1; m <= 8; m <<= 1)
#pragma unroll
            for (int i = 0; i < 8; ++i) {
                unsigned long long o = __shfl_xor(key[i], m, 64);
                if (o < key[i]) key[i] = o;
            }
        if (l15 == 0) {
#pragma unroll
            for (int m = 0; m < 2; ++m)
#pragma unroll
                for (int i = 0; i < 4; ++i)
                    keyBuf[q][m * 16 + qd * 4 + i] = key[m * 4 + i];
        }
        __syncthreads();
        if (tid < TPB) {
            unsigned long long k = keyBuf[0][tid];
            if (keyBuf[1][tid] < k) k = keyBuf[1][tid];
            if (keyBuf[2][tid] < k) k = keyBuf[2][tid];
            if (keyBuf[3][tid] < k) k = keyBuf[3][tid];
            const int idx = (int)(k & 1023ull);
            bestI_sh[tid] = idx;
            idxBuf[tid * NLVL + lvl] = idx;
            atomicAdd(&hist[idx], 1);
        }
        __syncthreads();

        // ---- epilogue: rotation trick + residual update (round-1 exact math) ----
        const float* cb = cbs + (size_t)lvl * KCB * DIM;
        for (int s2 = 0; s2 < 8; ++s2) {
            const int tl = q * 8 + s2;
            const int idx = bestI_sh[tl];
            const int e = tl & 15;
            float4 r4 = *(const float4*)&Rld[tl * DIM + ((lane ^ e) << 2)];
            r4.x *= 0.03125f; r4.y *= 0.03125f; r4.z *= 0.03125f; r4.w *= 0.03125f;
            float4 c4 = *(const float4*)(cb + (size_t)idx * DIM + lane * 4);
            float rr = r4.x * r4.x + r4.y * r4.y + r4.z * r4.z + r4.w * r4.w;
            float cc = c4.x * c4.x + c4.y * c4.y + c4.z * c4.z + c4.w * c4.w;
            float e0 = (c4.x - r4.x) * (c4.x - r4.x) + (c4.y - r4.y) * (c4.y - r4.y) +
                       (c4.z - r4.z) * (c4.z - r4.z) + (c4.w - r4.w) * (c4.w - r4.w);
            rr = wave_red(rr);
            cc = wave_red(cc);
            e0 = wave_red(e0);
            const float dx = fmaxf(sqrtf(rr), EPSV);
            const float dc = fmaxf(sqrtf(cc), EPSV);
            float4 u4 = make_float4(r4.x / dx, r4.y / dx, r4.z / dx, r4.w / dx);
            float4 q4 = make_float4(c4.x / dc, c4.y / dc, c4.z / dc, c4.w / dc);
            float4 w4 = make_float4(u4.x + q4.x, u4.y + q4.y, u4.z + q4.z, u4.w + q4.w);
            float ww = w4.x * w4.x + w4.y * w4.y + w4.z * w4.z + w4.w * w4.w;
            float xw = r4.x * w4.x + r4.y * w4.y + r4.z * w4.z + r4.w * w4.w;
            float xu = r4.x * u4.x + r4.y * u4.y + r4.z * u4.z + r4.w * u4.w;
            ww = wave_red(ww);
            xw = wave_red(xw);
            xu = wave_red(xu);
            const float dw = fmaxf(sqrtf(ww), EPSV);
            const float xwn = xw / dw;
            float4 wn = make_float4(w4.x / dw, w4.y / dw, w4.z / dw, w4.w / dw);
            float4 zst = make_float4(r4.x - 2.f * xwn * wn.x + 2.f * xu * q4.x,
                                     r4.y - 2.f * xwn * wn.y + 2.f * xu * q4.y,
                                     r4.z - 2.f * xwn * wn.z + 2.f * xu * q4.z,
                                     r4.w - 2.f * xwn * wn.w + 2.f * xu * q4.w);
            float4 rn = make_float4((r4.x - zst.x) * 32.f, (r4.y - zst.y) * 32.f,
                                    (r4.z - zst.z) * 32.f, (r4.w - zst.w) * 32.f);
            *(float4*)&Rld[tl * DIM + ((lane ^ e) << 2)] = rn;
            loss_acc += e0;
        }
        __syncthreads();
    }

    // ---- outputs: z_q = z + (sum_l c[idx_l] - z) ----
    for (int s2 = 0; s2 < 8; ++s2) {
        const int tl = q * 8 + s2;
        const size_t trow = t0 + tl;
        float4 z4 = *(const float4*)(z + trow * DIM + lane * 4);
        float4 qs = make_float4(0.f, 0.f, 0.f, 0.f);
#pragma unroll
        for (int lvl = 0; lvl < NLVL; ++lvl) {
            const int idx = idxBuf[tl * NLVL + lvl];
            float4 c4 = *(const float4*)(cbs + ((size_t)(lvl * KCB + idx)) * DIM + lane * 4);
            qs.x += c4.x; qs.y += c4.y; qs.z += c4.z; qs.w += c4.w;
        }
        float4 o = make_float4(z4.x + (qs.x - z4.x), z4.y + (qs.y - z4.y),
                               z4.z + (qs.z - z4.z), z4.w + (qs.w - z4.w));
        *(float4*)(out + trow * DIM + lane * 4) = o;
    }
    // indices as float, [N, 8]
    out[IDX_OFF + (size_t)(t0 + (tid >> 3)) * NLVL + (tid & 7)] = (float)idxBuf[tid];
    // histogram flush
#pragma unroll
    for (int i = 0; i < 4; ++i) {
        int b = tid + i * 256;
        int h = hist[b];
        if (h) atomicAdd(&gcounts[b], h);
    }
    // loss partial
    if (lane == 0) wpart[q] = loss_acc;
    __syncthreads();
    if (tid == 0) atomicAdd(gloss, wpart[0] + wpart[1] + wpart[2] + wpart[3]);
}

// ---------------- scalars: losses + perplexity ----------------
__global__ __launch_bounds__(256) void k_fin(const int* __restrict__ gcounts,
                                             const float* __restrict__ gloss,
                                             float* __restrict__ out) {
    __shared__ float part[4];
    const int tid = threadIdx.x, lane = tid & 63, wv = tid >> 6;
    float e = 0.f;
#pragma unroll
    for (int i = 0; i < 4; ++i) {
        float c = (float)gcounts[tid * 4 + i];
        float p = c * (1.f / 524288.f);
        if (p > 0.f) e += p * logf(p);
    }
    e = wave_red(e);
    if (lane == 0) part[wv] = e;
    __syncthreads();
    if (tid == 0) {
        float ent = -(part[0] + part[1] + part[2] + part[3]);
        float cbl = *gloss * (1.f / 16777216.f);
        out[SC_OFF + 0] = cbl + 0.25f * cbl;
        out[SC_OFF + 1] = cbl;
        out[SC_OFF + 2] = cbl;
        out[SC_OFF + 3] = expf(ent);
    }
}

extern "C" void kernel_launch(void* const* d_in, const int* in_sizes, int n_in,
                              void* d_out, int out_size, void* d_ws, size_t ws_size,
                              hipStream_t stream) {
    (void)in_sizes; (void)n_in; (void)out_size; (void)ws_size;
    const float* z = (const float*)d_in[0];
    const float* cbs = (const float*)d_in[1];
    float* out = (float*)d_out;
    half8* ws_b = (half8*)d_ws;                                    // 8 MB fragments
    float* csq = (float*)((char*)d_ws + (8u << 20));               // 32 KB
    int* gcounts = (int*)((char*)d_ws + (8u << 20) + 32768);       // 4 KB
    float* gloss = (float*)((char*)d_ws + (8u << 20) + 32768 + 4096);

    hipLaunchKernelGGL(k_prep, dim3(512), dim3(256), 0, stream, cbs, ws_b);
    hipLaunchKernelGGL(k_csq, dim3(2048), dim3(256), 0, stream, cbs, csq, gcounts, gloss);
    hipLaunchKernelGGL(k_main, dim3(2048), dim3(256), 0, stream, z, cbs, ws_b, csq, out,
                       gcounts, gloss);
    hipLaunchKernelGGL(k_fin, dim3(1), dim3(256), 0, stream, gcounts, gloss, out);
}

// Round 4
// 1395.567 us; speedup vs baseline: 4.2293x; 1.0455x over previous
//
#include <hip/hip_runtime.h>

#define N_TOK 65536
#define DIM 256
#define KCB 1024
#define NLVL 8
#define TPB 64                        // tokens per block (k_main)
#define ND_OUT (N_TOK * DIM)          // 16777216
#define IDX_OFF ND_OUT
#define SC_OFF (ND_OUT + N_TOK * NLVL) // 17301504
#define EPSV 1e-6f

typedef _Float16 half8 __attribute__((ext_vector_type(8)));
typedef float f32x4 __attribute__((ext_vector_type(4)));

__device__ __forceinline__ float wave_red(float v) {
    v += __shfl_xor(v, 32, 64);
    v += __shfl_xor(v, 16, 64);
    v += __shfl_xor(v, 8, 64);
    v += __shfl_xor(v, 4, 64);
    v += __shfl_xor(v, 2, 64);
    v += __shfl_xor(v, 1, 64);
    return v;
}

// order-preserving float->uint map (monotone increasing)
__device__ __forceinline__ unsigned int ordf(float d) {
    unsigned int u = __float_as_uint(d);
    return (u & 0x80000000u) ? ~u : (u ^ 0x80000000u);
}

// ---------------- B-fragment precompute (fp16 hi/lo RNE split, scaled) ----------------
// layout: frag F = (lvl*8 + s)*64 + ntg ; at F*128: [hi: 64 x half8][lo: 64 x half8]
// lane l holds C[code = ntg*16 + (l&15)][dim = s*32 + (l>>4)*8 + j] * 2^(lvl+5)
__global__ __launch_bounds__(256) void k_prep(const float* __restrict__ cbs,
                                              half8* __restrict__ ws_b) {
    const int lvl = blockIdx.x >> 6, ntg = blockIdx.x & 63;
    const int lane = threadIdx.x & 63, sg = threadIdx.x >> 6;
    const float sc = (float)(1 << (lvl + 5));
#pragma unroll
    for (int ss = 0; ss < 2; ++ss) {
        const int s = sg + ss * 4;
        const int code = ntg * 16 + (lane & 15);
        const int d0 = s * 32 + (lane >> 4) * 8;
        const float* p = cbs + ((size_t)(lvl * KCB + code)) * DIM + d0;
        const float4 va = *(const float4*)p;
        const float4 vb = *(const float4*)(p + 4);
        float f[8] = {va.x, va.y, va.z, va.w, vb.x, vb.y, vb.z, vb.w};
        half8 h, l;
#pragma unroll
        for (int j = 0; j < 8; ++j) {
            float fs = f[j] * sc;
            _Float16 hh = (_Float16)fs;          // RNE
            h[j] = hh;
            l[j] = (_Float16)(fs - (float)hh);   // RNE
        }
        const size_t base = ((size_t)((lvl * 8 + s) * 64 + ntg)) * 128;
        ws_b[base + lane] = h;
        ws_b[base + 64 + lane] = l;
    }
}

// ---------------- scaled c_sq + ws zeroing ----------------
__global__ __launch_bounds__(256) void k_csq(const float* __restrict__ cbs,
                                             float* __restrict__ csq_s,
                                             int* __restrict__ gcounts,
                                             float* __restrict__ gloss) {
    const int tid = threadIdx.x;
    const int wv = tid >> 6, lane = tid & 63;
    const int code = blockIdx.x * 4 + wv; // 0..8191 (lvl*1024 + k)
    const float4 v = *(const float4*)(cbs + (size_t)code * DIM + lane * 4);
    float s = v.x * v.x + v.y * v.y + v.z * v.z + v.w * v.w;
    s = wave_red(s);
    const int lvl = code >> 10;
    if (lane == 0) csq_s[code] = s * (float)(1 << (10 + lvl));
    if (blockIdx.x == 0) {
#pragma unroll
        for (int i = 0; i < 4; ++i) gcounts[tid + i * 256] = 0;
        if (tid == 0) *gloss = 0.f;
    }
}

// ---------------- fused RVQ main ----------------
// 512 threads = 8 waves; block owns 64 tokens (M=64, 4 m-tiles of 16);
// wave w covers codes [w*128, w*128+128) = 8 code-tiles of 16.
__global__ __launch_bounds__(512, 2) void k_main(const float* __restrict__ z,
                                                 const float* __restrict__ cbs,
                                                 const half8* __restrict__ ws_b,
                                                 const float* __restrict__ csq_s,
                                                 float* __restrict__ out,
                                                 int* __restrict__ gcounts,
                                                 float* __restrict__ gloss) {
    __shared__ __align__(16) float Rld[TPB * DIM];     // 64 KB, x32-scaled, col4 = k4 ^ (t&15)
    __shared__ unsigned long long keyBuf[8][TPB];      // 4 KB
    __shared__ int bestI_sh[TPB];
    __shared__ int idxBuf[TPB * NLVL];                 // 2 KB
    __shared__ int hist[KCB];                          // 4 KB
    __shared__ float wpart[8];

    const int tid = threadIdx.x;
    const int lane = tid & 63, w = tid >> 6;
    const int l15 = lane & 15, qd = lane >> 4;
    const int t0 = blockIdx.x * TPB;

    // stage z -> Rld, pre-scaled by 32 (exact pow2), swizzled
#pragma unroll
    for (int i = 0; i < 8; ++i) {
        int fi = tid + i * 512;          // float4 index 0..4095
        int t = fi >> 6, k4 = fi & 63;
        float4 v = *(const float4*)(z + (size_t)(t0 + t) * DIM + k4 * 4);
        v.x *= 32.f; v.y *= 32.f; v.z *= 32.f; v.w *= 32.f;
        *(float4*)&Rld[t * DIM + ((k4 ^ (t & 15)) << 2)] = v;
    }
#pragma unroll
    for (int i = 0; i < 2; ++i) hist[tid + i * 512] = 0;
    float loss_acc = 0.f;

    // B prefetch chain: carried across nt, s, AND levels (frags contiguous in (lvl,s))
    const half8* pbw = ws_b + (size_t)(w * 8) * 128 + lane;
    half8 bh = pbw[0], bl = pbw[64];
    __syncthreads();

    for (int lvl = 0; lvl < NLVL; ++lvl) {
        float bd[16];
        int bi[16];
#pragma unroll
        for (int i = 0; i < 16; ++i) { bd[i] = 3.402823466e38f; bi[i] = 0; }

        f32x4 acc[8][4];
#pragma unroll
        for (int nt = 0; nt < 8; ++nt)
#pragma unroll
            for (int m = 0; m < 4; ++m) acc[nt][m] = (f32x4){0.f, 0.f, 0.f, 0.f};

#pragma unroll 1
        for (int s = 0; s < 8; ++s) {
            // ---- A fragments for this s: read swizzled Rld, RNE hi/lo split ----
            half8 Ah[4], Al[4];
#pragma unroll
            for (int m = 0; m < 4; ++m) {
                const int row = (m * 16 + l15) * DIM;
                const int k4 = 8 * s + 2 * qd;
                float4 va = *(const float4*)&Rld[row + ((k4 ^ l15) << 2)];
                float4 vb = *(const float4*)&Rld[row + (((k4 + 1) ^ l15) << 2)];
                float f[8] = {va.x, va.y, va.z, va.w, vb.x, vb.y, vb.z, vb.w};
                half8 h, l;
#pragma unroll
                for (int j = 0; j < 8; ++j) {
                    _Float16 hh = (_Float16)f[j];
                    h[j] = hh;
                    l[j] = (_Float16)(f[j] - (float)hh);
                }
                Ah[m] = h;
                Al[m] = l;
            }
            // ---- B stream (L2), software-pipelined, 16 MFMA per load pair ----
            const half8* pb = ws_b + (((size_t)(lvl * 8 + s)) * 64 + w * 8) * 128 + lane;
#pragma unroll
            for (int nt = 0; nt < 8; ++nt) {
                const int off = (nt < 7) ? (nt + 1) * 128 : 64 * 128; // next tile / next (s|lvl)
                half8 nbh = pb[off];
                half8 nbl = pb[off + 64];
#pragma unroll
                for (int m = 0; m < 4; ++m)
                    acc[nt][m] = __builtin_amdgcn_mfma_f32_16x16x32_f16(Ah[m], bh, acc[nt][m], 0, 0, 0);
#pragma unroll
                for (int m = 0; m < 4; ++m)
                    acc[nt][m] = __builtin_amdgcn_mfma_f32_16x16x32_f16(Al[m], bh, acc[nt][m], 0, 0, 0);
#pragma unroll
                for (int m = 0; m < 4; ++m)
                    acc[nt][m] = __builtin_amdgcn_mfma_f32_16x16x32_f16(Ah[m], bl, acc[nt][m], 0, 0, 0);
#pragma unroll
                for (int m = 0; m < 4; ++m)
                    acc[nt][m] = __builtin_amdgcn_mfma_f32_16x16x32_f16(Al[m], bl, acc[nt][m], 0, 0, 0);
                bh = nbh;
                bl = nbl;
            }
        }
        // ---- distances + running argmin (tie -> smaller index) ----
        {
            const float* csqp = csq_s + lvl * KCB + w * 128 + l15;
#pragma unroll
            for (int nt = 0; nt < 8; ++nt) {
                const float cs = csqp[nt * 16];
                const int code = w * 128 + nt * 16 + l15;
#pragma unroll
                for (int m = 0; m < 4; ++m)
#pragma unroll
                    for (int i = 0; i < 4; ++i) {
                        float d = fmaf(-2.f, acc[nt][m][i], cs);
                        if (d < bd[m * 4 + i]) { bd[m * 4 + i] = d; bi[m * 4 + i] = code; }
                    }
            }
        }
        // ---- argmin cross-lane reduce over the 16 code-lanes ----
        unsigned long long key[16];
#pragma unroll
        for (int i = 0; i < 16; ++i)
            key[i] = (((unsigned long long)ordf(bd[i])) << 10) | (unsigned long long)bi[i];
#pragma unroll
        for (int m = 1; m <= 8; m <<= 1)
#pragma unroll
            for (int i = 0; i < 16; ++i) {
                unsigned long long o = __shfl_xor(key[i], m, 64);
                if (o < key[i]) key[i] = o;
            }
        if (l15 == 0) {
#pragma unroll
            for (int m = 0; m < 4; ++m)
#pragma unroll
                for (int i = 0; i < 4; ++i)
                    keyBuf[w][m * 16 + qd * 4 + i] = key[m * 4 + i];
        }
        __syncthreads();
        if (tid < TPB) {
            unsigned long long k = keyBuf[0][tid];
#pragma unroll
            for (int ww = 1; ww < 8; ++ww)
                if (keyBuf[ww][tid] < k) k = keyBuf[ww][tid];
            const int idx = (int)(k & 1023ull);
            bestI_sh[tid] = idx;
            idxBuf[tid * NLVL + lvl] = idx;
            atomicAdd(&hist[idx], 1);
        }
        __syncthreads();

        // ---- epilogue: rotation trick + residual update (round-1 exact math) ----
        const float* cb = cbs + (size_t)lvl * KCB * DIM;
        for (int s2 = 0; s2 < 8; ++s2) {
            const int tl = w * 8 + s2;
            const int idx = bestI_sh[tl];
            const int e = tl & 15;
            float4 r4 = *(const float4*)&Rld[tl * DIM + ((lane ^ e) << 2)];
            r4.x *= 0.03125f; r4.y *= 0.03125f; r4.z *= 0.03125f; r4.w *= 0.03125f;
            float4 c4 = *(const float4*)(cb + (size_t)idx * DIM + lane * 4);
            float rr = r4.x * r4.x + r4.y * r4.y + r4.z * r4.z + r4.w * r4.w;
            float cc = c4.x * c4.x + c4.y * c4.y + c4.z * c4.z + c4.w * c4.w;
            float e0 = (c4.x - r4.x) * (c4.x - r4.x) + (c4.y - r4.y) * (c4.y - r4.y) +
                       (c4.z - r4.z) * (c4.z - r4.z) + (c4.w - r4.w) * (c4.w - r4.w);
            rr = wave_red(rr);
            cc = wave_red(cc);
            e0 = wave_red(e0);
            const float dx = fmaxf(sqrtf(rr), EPSV);
            const float dc = fmaxf(sqrtf(cc), EPSV);
            float4 u4 = make_float4(r4.x / dx, r4.y / dx, r4.z / dx, r4.w / dx);
            float4 q4 = make_float4(c4.x / dc, c4.y / dc, c4.z / dc, c4.w / dc);
            float4 w4 = make_float4(u4.x + q4.x, u4.y + q4.y, u4.z + q4.z, u4.w + q4.w);
            float ww = w4.x * w4.x + w4.y * w4.y + w4.z * w4.z + w4.w * w4.w;
            float xw = r4.x * w4.x + r4.y * w4.y + r4.z * w4.z + r4.w * w4.w;
            float xu = r4.x * u4.x + r4.y * u4.y + r4.z * u4.z + r4.w * u4.w;
            ww = wave_red(ww);
            xw = wave_red(xw);
            xu = wave_red(xu);
            const float dw = fmaxf(sqrtf(ww), EPSV);
            const float xwn = xw / dw;
            float4 wn = make_float4(w4.x / dw, w4.y / dw, w4.z / dw, w4.w / dw);
            float4 zst = make_float4(r4.x - 2.f * xwn * wn.x + 2.f * xu * q4.x,
                                     r4.y - 2.f * xwn * wn.y + 2.f * xu * q4.y,
                                     r4.z - 2.f * xwn * wn.z + 2.f * xu * q4.z,
                                     r4.w - 2.f * xwn * wn.w + 2.f * xu * q4.w);
            float4 rn = make_float4((r4.x - zst.x) * 32.f, (r4.y - zst.y) * 32.f,
                                    (r4.z - zst.z) * 32.f, (r4.w - zst.w) * 32.f);
            *(float4*)&Rld[tl * DIM + ((lane ^ e) << 2)] = rn;
            loss_acc += e0;
        }
        __syncthreads();
    }

    // ---- outputs: z_q = z + (sum_l c[idx_l] - z) ----
    for (int s2 = 0; s2 < 8; ++s2) {
        const int tl = w * 8 + s2;
        const size_t trow = t0 + tl;
        float4 z4 = *(const float4*)(z + trow * DIM + lane * 4);
        float4 qs = make_float4(0.f, 0.f, 0.f, 0.f);
#pragma unroll
        for (int lvl = 0; lvl < NLVL; ++lvl) {
            const int idx = idxBuf[tl * NLVL + lvl];
            float4 c4 = *(const float4*)(cbs + ((size_t)(lvl * KCB + idx)) * DIM + lane * 4);
            qs.x += c4.x; qs.y += c4.y; qs.z += c4.z; qs.w += c4.w;
        }
        float4 o = make_float4(z4.x + (qs.x - z4.x), z4.y + (qs.y - z4.y),
                               z4.z + (qs.z - z4.z), z4.w + (qs.w - z4.w));
        *(float4*)(out + trow * DIM + lane * 4) = o;
    }
    // indices as float, [N, 8]
    out[IDX_OFF + (size_t)(t0 + (tid >> 3)) * NLVL + (tid & 7)] = (float)idxBuf[tid];
    // histogram flush
#pragma unroll
    for (int i = 0; i < 2; ++i) {
        int b = tid + i * 512;
        int h = hist[b];
        if (h) atomicAdd(&gcounts[b], h);
    }
    // loss partial
    if (lane == 0) wpart[w] = loss_acc;
    __syncthreads();
    if (tid == 0) {
        float sum = 0.f;
#pragma unroll
        for (int i = 0; i < 8; ++i) sum += wpart[i];
        atomicAdd(gloss, sum);
    }
}

// ---------------- scalars: losses + perplexity ----------------
__global__ __launch_bounds__(256) void k_fin(const int* __restrict__ gcounts,
                                             const float* __restrict__ gloss,
                                             float* __restrict__ out) {
    __shared__ float part[4];
    const int tid = threadIdx.x, lane = tid & 63, wv = tid >> 6;
    float e = 0.f;
#pragma unroll
    for (int i = 0; i < 4; ++i) {
        float c = (float)gcounts[tid * 4 + i];
        float p = c * (1.f / 524288.f);
        if (p > 0.f) e += p * logf(p);
    }
    e = wave_red(e);
    if (lane == 0) part[wv] = e;
    __syncthreads();
    if (tid == 0) {
        float ent = -(part[0] + part[1] + part[2] + part[3]);
        float cbl = *gloss * (1.f / 16777216.f);
        out[SC_OFF + 0] = cbl + 0.25f * cbl;
        out[SC_OFF + 1] = cbl;
        out[SC_OFF + 2] = cbl;
        out[SC_OFF + 3] = expf(ent);
    }
}

extern "C" void kernel_launch(void* const* d_in, const int* in_sizes, int n_in,
                              void* d_out, int out_size, void* d_ws, size_t ws_size,
                              hipStream_t stream) {
    (void)in_sizes; (void)n_in; (void)out_size; (void)ws_size;
    const float* z = (const float*)d_in[0];
    const float* cbs = (const float*)d_in[1];
    float* out = (float*)d_out;
    half8* ws_b = (half8*)d_ws;                                    // 8 MB fragments
    float* csq = (float*)((char*)d_ws + (8u << 20));               // 32 KB
    int* gcounts = (int*)((char*)d_ws + (8u << 20) + 32768);       // 4 KB
    float* gloss = (float*)((char*)d_ws + (8u << 20) + 32768 + 4096);

    hipLaunchKernelGGL(k_prep, dim3(512), dim3(256), 0, stream, cbs, ws_b);
    hipLaunchKernelGGL(k_csq, dim3(2048), dim3(256), 0, stream, cbs, csq, gcounts, gloss);
    hipLaunchKernelGGL(k_main, dim3(1024), dim3(512), 0, stream, z, cbs, ws_b, csq, out,
                       gcounts, gloss);
    hipLaunchKernelGGL(k_fin, dim3(1), dim3(256), 0, stream, gcounts, gloss, out);
}